// Round 1
// baseline (459.642 us; speedup 1.0000x reference)
//
#include <hip/hip_runtime.h>
#include <cmath>

typedef __bf16 bf16;
typedef __bf16 bf16x8 __attribute__((ext_vector_type(8)));
typedef float f32x4 __attribute__((ext_vector_type(4)));

// Problem constants
// B=16, C_IN=256, H=W=64, C_OUT=256, K=3x3, stride 1, pad 1, CURV=1

// ---------------------------------------------------------------------------
// Weight transform: z[k=c*9+tap][co] (fp32) -> zt[tap][co][c] (bf16)
__global__ void k_prep_zt(const float* __restrict__ z, bf16* __restrict__ zt) {
    int bid = blockIdx.x;          // 0..2303 = tap*256 + co
    int tap = bid >> 8, co = bid & 255;
    int c = threadIdx.x;
    float v = z[(size_t)(c * 9 + tap) * 256 + co];
    zt[(size_t)bid * 256 + c] = (bf16)v;
}

// Column constants: zn[co]=max(||z[:,co]||,eps), ch=cosh(2r), sh=sinh(2r)
__global__ void k_prep_cols(const float* __restrict__ z, const float* __restrict__ r,
                            float* __restrict__ zn, float* __restrict__ ch,
                            float* __restrict__ sh) {
    __shared__ float red[256];
    int co = blockIdx.x, t = threadIdx.x;
    float s = 0.f;
    for (int i = 0; i < 9; ++i) {
        float v = z[(size_t)(i * 256 + t) * 256 + co];
        s += v * v;
    }
    red[t] = s;
    __syncthreads();
    for (int off = 128; off >= 1; off >>= 1) {
        if (t < off) red[t] += red[t + off];
        __syncthreads();
    }
    if (t == 0) {
        zn[co] = fmaxf(sqrtf(red[0]), 1e-15f);
        float tc = 2.f * r[co];
        ch[co] = coshf(tc);
        sh[co] = sinhf(tc);
    }
}

// ---------------------------------------------------------------------------
// logmap0 * beta-ratio, transpose [B,C,HW] -> vt[B,HW,C] bf16, and per-pixel
// sq = sum_c v^2 (fp32).
__global__ void k_logmap(const float* __restrict__ x, unsigned int* __restrict__ vt_u,
                         float* __restrict__ sq, float Rbeta) {
    __shared__ float tile[256][33];
    __shared__ float red[8][32];
    __shared__ float afac[32];
    int tid = threadIdx.x;
    int blk = blockIdx.x;
    int b = blk >> 7;               // 128 tiles of 32 pixels per image
    int pix0 = (blk & 127) << 5;

    // Phase 1: coalesced load of 256ch x 32pix
    for (int it = 0; it < 32; ++it) {
        int c = it * 8 + (tid >> 5);
        int p = tid & 31;
        tile[c][p] = x[((size_t)b * 256 + c) * 4096 + pix0 + p];
    }
    __syncthreads();

    // Phase 2: per-pixel sumsq over channels
    {
        int part = tid >> 5, p = tid & 31;
        float s = 0.f;
        for (int i = 0; i < 32; ++i) {
            float v = tile[part * 32 + i][p];
            s += v * v;
        }
        red[part][p] = s;
    }
    __syncthreads();
    if (tid < 32) {
        float n2 = 0.f;
        for (int i = 0; i < 8; ++i) n2 += red[i][tid];
        float n = sqrtf(n2);
        float nc = fmaxf(n, 1e-15f);
        float a = atanhf(fminf(nc, 0.9999999f)) / nc * Rbeta;
        afac[tid] = a;
        sq[(size_t)b * 4096 + pix0 + tid] = a * a * n2;
    }
    __syncthreads();

    // Phase 3: scale + bf16 pack, coalesced along channels
    for (int it = 0; it < 16; ++it) {
        int idx = it * 256 + tid;
        int p = idx >> 7;
        int cp = idx & 127;
        float a = afac[p];
        float v0 = a * tile[2 * cp][p];
        float v1 = a * tile[2 * cp + 1][p];
        union { bf16 h[2]; unsigned int u; } pk;
        pk.h[0] = (bf16)v0;
        pk.h[1] = (bf16)v1;
        vt_u[((size_t)b * 4096 + pix0 + p) * 128 + cp] = pk.u;
    }
}

// 3x3 zero-padded box sum of sq -> nusq (= ||u||^2 per output pixel)
__global__ void k_boxsum(const float* __restrict__ sq, float* __restrict__ nusq) {
    int idx = blockIdx.x * 256 + threadIdx.x;
    int b = idx >> 12, hw = idx & 4095, h = hw >> 6, w = hw & 63;
    const float* s = sq + ((size_t)b << 12);
    float acc = 0.f;
    for (int dh = -1; dh <= 1; ++dh) {
        int hh = h + dh;
        if ((unsigned)hh >= 64u) continue;
        for (int dw = -1; dw <= 1; ++dw) {
            int ww = w + dw;
            if ((unsigned)ww >= 64u) continue;
            acc += s[hh * 64 + ww];
        }
    }
    nusq[idx] = acc;
}

// ---------------------------------------------------------------------------
// Fused implicit-GEMM conv + hyperbolic FC epilogue.
// One block per (b,h) image row: 64 pixels x 256 out-channels.
// 8 waves: wm in {0,1} (32 pixels each), wn in {0..3} (64 cols each).
__launch_bounds__(512)
__global__ void k_hconv(const bf16* __restrict__ vt, const bf16* __restrict__ zt,
                        const float* __restrict__ nusq,
                        const float* __restrict__ znp, const float* __restrict__ chp,
                        const float* __restrict__ shp, float* __restrict__ out) {
    __shared__ float s_lds[64];
    __shared__ float lam_lds[64];
    __shared__ float red[64][4];

    int tid = threadIdx.x;
    int bh = blockIdx.x;           // b*64 + h
    int b = bh >> 6, h = bh & 63;

    if (tid < 64) {
        float q = nusq[(size_t)bh * 64 + tid];
        float nu = sqrtf(q);
        float ncl = fmaxf(nu, 1e-15f);
        float t = tanhf(ncl);
        float s = t / ncl;           // expmap scale
        s_lds[tid] = s;
        lam_lds[tid] = 2.f / (1.f - s * s * q);   // lam = 2/(1 - tanh^2)
    }

    int wave = tid >> 6, lane = tid & 63;
    int wn = wave & 3, wm = wave >> 2;
    int lrow = lane & 15, lk = lane >> 4;

    f32x4 acc[2][4];
#pragma unroll
    for (int m = 0; m < 2; ++m)
#pragma unroll
        for (int n = 0; n < 4; ++n) acc[m][n] = (f32x4){0.f, 0.f, 0.f, 0.f};

    bf16x8 zf;
#pragma unroll
    for (int e = 0; e < 8; ++e) zf[e] = (bf16)0.0f;

    const bf16* vbase = vt + (size_t)b * 4096 * 256;
    __syncthreads();   // s_lds/lam_lds visible to epilogue

    for (int cb = 0; cb < 8; ++cb) {
        int c0 = cb * 32 + lk * 8;
#pragma unroll
        for (int tap = 0; tap < 9; ++tap) {
            int dh = tap / 3 - 1, dw = tap % 3 - 1;
            int hh = h + dh;
            if ((unsigned)hh >= 64u) continue;   // uniform

            bf16x8 a[2];
#pragma unroll
            for (int m = 0; m < 2; ++m) {
                int ww = wm * 32 + m * 16 + lrow + dw;
                bool ok = (unsigned)ww < 64u;
                const bf16x8* ap = (const bf16x8*)(vbase +
                    ((size_t)(hh * 64 + (ok ? ww : 0))) * 256 + c0);
                bf16x8 av = *ap;
                a[m] = ok ? av : zf;
            }
            bf16x8 bb[4];
#pragma unroll
            for (int n = 0; n < 4; ++n) {
                int co = wn * 64 + n * 16 + lrow;
                bb[n] = *(const bf16x8*)(zt + ((size_t)(tap * 256 + co)) * 256 + c0);
            }
#pragma unroll
            for (int m = 0; m < 2; ++m)
#pragma unroll
                for (int n = 0; n < 4; ++n)
                    acc[m][n] = __builtin_amdgcn_mfma_f32_16x16x32_bf16(
                        a[m], bb[n], acc[m][n], 0, 0, 0);
        }
    }

    // ---------------- epilogue ----------------
    float znv[4], chv[4], shv[4];
#pragma unroll
    for (int n = 0; n < 4; ++n) {
        int co = wn * 64 + n * 16 + lrow;
        znv[n] = znp[co];
        chv[n] = chp[co];
        shv[n] = shp[co];
    }

    float part[2][4];
#pragma unroll
    for (int m = 0; m < 2; ++m) {
#pragma unroll
        for (int r = 0; r < 4; ++r) {
            int wp = wm * 32 + m * 16 + 4 * lk + r;
            float s = s_lds[wp], lam = lam_lds[wp];
            float psum = 0.f;
#pragma unroll
            for (int n = 0; n < 4; ++n) {
                float xz = s * acc[m][n][r];
                float inner = lam * xz / znv[n] * chv[n] - (lam - 1.f) * shv[n];
                float vhp = 2.f * znv[n] * asinhf(inner);
                float w = sinhf(vhp);
                acc[m][n][r] = w;          // reuse acc to hold w
                psum += w * w;
            }
            // reduce over the 16 lanes (same pixel, different cols)
            psum += __shfl_xor(psum, 1);
            psum += __shfl_xor(psum, 2);
            psum += __shfl_xor(psum, 4);
            psum += __shfl_xor(psum, 8);
            part[m][r] = psum;
        }
    }
    if (lrow == 0) {
#pragma unroll
        for (int m = 0; m < 2; ++m)
#pragma unroll
            for (int r = 0; r < 4; ++r) {
                int wp = wm * 32 + m * 16 + 4 * lk + r;
                red[wp][wn] = part[m][r];
            }
    }
    __syncthreads();

    float* ob = out + (size_t)b * 256 * 4096 + h * 64;
#pragma unroll
    for (int m = 0; m < 2; ++m) {
#pragma unroll
        for (int n = 0; n < 4; ++n) {
            int co = wn * 64 + n * 16 + lrow;
            f32x4 o;
#pragma unroll
            for (int r = 0; r < 4; ++r) {
                int wp = wm * 32 + m * 16 + 4 * lk + r;
                float tot = red[wp][0] + red[wp][1] + red[wp][2] + red[wp][3];
                o[r] = acc[m][n][r] / (1.f + sqrtf(1.f + tot));
            }
            *(f32x4*)(ob + (size_t)co * 4096 + wm * 32 + m * 16 + 4 * lk) = o;
        }
    }
}

// ---------------------------------------------------------------------------
extern "C" void kernel_launch(void* const* d_in, const int* in_sizes, int n_in,
                              void* d_out, int out_size, void* d_ws, size_t ws_size,
                              hipStream_t stream) {
    const float* x = (const float*)d_in[0];   // [16,256,64,64]
    const float* z = (const float*)d_in[1];   // [2304,256]
    const float* r = (const float*)d_in[2];   // [256]
    float* out = (float*)d_out;               // [16,256,64,64]

    char* ws = (char*)d_ws;
    // layout (16B-aligned):
    bf16* vt = (bf16*)ws;                         // 33,554,432 B
    float* sq = (float*)(ws + 33554432);          //    262,144 B
    float* nusq = (float*)(ws + 33816576);        //    262,144 B
    bf16* zt = (bf16*)(ws + 34078720);            //  1,179,648 B
    float* zn = (float*)(ws + 35258368);          //      1,024 B
    float* ch = (float*)(ws + 35259392);          //      1,024 B
    float* sh = (float*)(ws + 35260416);          //      1,024 B
    if (ws_size < 35261440) return;

    // beta(1152,0.5)/beta(128,0.5)
    double bni = lgamma(128.0) + lgamma(0.5) - lgamma(128.5);
    double bn = lgamma(1152.0) + lgamma(0.5) - lgamma(1152.5);
    float Rbeta = (float)exp(bn - bni);

    k_prep_zt<<<2304, 256, 0, stream>>>(z, zt);
    k_prep_cols<<<256, 256, 0, stream>>>(z, r, zn, ch, sh);
    k_logmap<<<2048, 256, 0, stream>>>(x, (unsigned int*)vt, sq, Rbeta);
    k_boxsum<<<256, 256, 0, stream>>>(sq, nusq);
    k_hconv<<<1024, 512, 0, stream>>>(vt, zt, nusq, zn, ch, sh, out);
}